// Round 17
// baseline (167.995 us; speedup 1.0000x reference)
//
#include <hip/hip_runtime.h>

#define BN 32768
#define NB 16
#define NN 2048
#define CC 256
#define JT 64
#define NTILES (NN / JT)

using short8  = __attribute__((ext_vector_type(8))) short;
using floatx4 = __attribute__((ext_vector_type(4))) float;

__device__ __forceinline__ unsigned short f2bf(float f) {
  unsigned u = __builtin_bit_cast(unsigned, f);
  u += 0x7fffu + ((u >> 16) & 1u);
  return (unsigned short)(u >> 16);
}
__device__ __forceinline__ float bf2f(unsigned short h) {
  unsigned u = ((unsigned)h) << 16;
  return __builtin_bit_cast(float, u);
}
__device__ __forceinline__ unsigned pk4fp8(float a, float b, float c, float d) {
  unsigned u = __builtin_amdgcn_cvt_pk_fp8_f32(c, d, 0, true);
  return __builtin_amdgcn_cvt_pk_fp8_f32(a, b, (int)u, false);
}
__device__ __forceinline__ long lo64(uint4 v) {
  uint2 t; t.x = v.x; t.y = v.y; return __builtin_bit_cast(long, t);
}
__device__ __forceinline__ long hi64(uint4 v) {
  uint2 t; t.x = v.z; t.y = v.w; return __builtin_bit_cast(long, t);
}
__device__ __forceinline__ void gll16(const void* g, void* l) {
  __builtin_amdgcn_global_load_lds(
      (const __attribute__((address_space(1))) void*)g,
      (__attribute__((address_space(3))) void*)l, 16, 0, 0);
}
__device__ __forceinline__ float silu(float h) {
  return h / (1.0f + __expf(-h));
}

// --- weight transposes via LDS tiles (coalesced both sides), fp32 KxN -> bf16 NxK ---
__global__ __launch_bounds__(256) void wconv_kernel(
    const float* __restrict__ wh, const float* __restrict__ wkv,
    const float* __restrict__ wp,
    unsigned short* __restrict__ wTh, unsigned short* __restrict__ wTkv,
    unsigned short* __restrict__ wTp) {
  __shared__ float T[64][65];
  int bid = blockIdx.x;
  const float* src; unsigned short* dst; int N, kt, nt;
  if (bid < 32)      { src = wh;  dst = wTh;  N = 512; kt = bid >> 3;        nt = bid & 7; }
  else if (bid < 48) { src = wkv; dst = wTkv; N = 256; kt = (bid - 32) >> 2; nt = (bid - 32) & 3; }
  else               { src = wp;  dst = wTp;  N = 256; kt = (bid - 48) >> 2; nt = (bid - 48) & 3; }
  int k0 = kt * 64, n0 = nt * 64;
  int t = threadIdx.x;
  int r = t >> 2, c0 = (t & 3) * 16;
#pragma unroll
  for (int e = 0; e < 4; ++e)
    *(float4*)(&T[r][c0 + e * 4]) =
        *(const float4*)(src + (size_t)(k0 + r) * N + n0 + c0 + e * 4);
  __syncthreads();
#pragma unroll
  for (int e = 0; e < 16; ++e)
    dst[(size_t)(n0 + r) * 256 + k0 + c0 + e] = f2bf(T[c0 + e][r]);
}

// ==== fused producer (R15 config): LN once + v + gate + qk, m-tile 64, normed LDS-only ====
__global__ __launch_bounds__(256) void producer_kernel(
    const float* __restrict__ x, const float* __restrict__ lw,
    const float* __restrict__ lb,
    const unsigned short* __restrict__ wTh, const float* __restrict__ bh,
    const unsigned short* __restrict__ wTkv,
    const float* __restrict__ gamma, const float* __restrict__ beta,
    unsigned char* __restrict__ vB, unsigned short* __restrict__ gout,
    unsigned char* __restrict__ qout, unsigned char* __restrict__ kout) {
  __shared__ unsigned short Al[64 * 256];   // 32 KB swizzled bf16 normed tile
  const int t = threadIdx.x;
  const int mb = blockIdx.x * 64;
  // ---- LN: 4 threads/row, two reads (no register retention of x) ----
  {
    int r = t >> 2, q = t & 3;
    const float4* xp = (const float4*)(x + (size_t)(mb + r) * CC + q * 64);
    float s = 0.0f, s2 = 0.0f;
#pragma unroll
    for (int f = 0; f < 16; ++f) {
      float4 v = xp[f];
      s  += v.x + v.y + v.z + v.w;
      s2 += v.x * v.x + v.y * v.y + v.z * v.z + v.w * v.w;
    }
    s  += __shfl_xor(s, 1);  s  += __shfl_xor(s, 2);
    s2 += __shfl_xor(s2, 1); s2 += __shfl_xor(s2, 2);
    float mu = s * (1.0f / CC);
    float rs = rsqrtf(s2 * (1.0f / CC) - mu * mu + 1e-5f);
    const float4* lwp = (const float4*)(lw + q * 64);
    const float4* lbp = (const float4*)(lb + q * 64);
    asm volatile("" ::: "memory");   // force re-read instead of retaining xv
#pragma unroll
    for (int f = 0; f < 16; ++f) {
      float4 v = xp[f];
      float4 w = lwp[f], b = lbp[f];
      ushort4 o;
      o.x = f2bf((v.x - mu) * rs * w.x + b.x);
      o.y = f2bf((v.y - mu) * rs * w.y + b.y);
      o.z = f2bf((v.z - mu) * rs * w.z + b.z);
      o.w = f2bf((v.w - mu) * rs * w.w + b.w);
      int c16 = q * 8 + (f >> 1);
      *(ushort4*)((char*)Al + r * 512 + ((c16 ^ (r & 7)) * 16) + (f & 1) * 8) = o;
    }
  }
  __syncthreads();
  const int wave = t >> 6, lane = t & 63;
  const int m = lane & 15, g4 = lane >> 4;
  const int sw = (m >> 1) & 3;
  // ---------- pass 1: v = silu(normed @ wh[:,0:256] + b) -> fp8 image ----------
  {
    floatx4 acc[4][4] = {};
#pragma unroll
    for (int ks = 0; ks < 8; ++ks) {
      short8 af[4], bf[4];
#pragma unroll
      for (int i = 0; i < 4; ++i)
        af[i] = *(const short8*)((const char*)Al + (i * 16 + m) * 512 +
                                 (((ks * 4 + g4) ^ (m & 7)) * 16));
#pragma unroll
      for (int j = 0; j < 4; ++j)
        bf[j] = *(const short8*)(wTh + (size_t)(wave * 64 + j * 16 + m) * 256 + ks * 32 + g4 * 8);
#pragma unroll
      for (int i = 0; i < 4; ++i)
#pragma unroll
        for (int j = 0; j < 4; ++j)
          acc[i][j] = __builtin_amdgcn_mfma_f32_16x16x32_bf16(af[i], bf[j], acc[i][j], 0, 0, 0);
    }
    const size_t tb = ((size_t)(mb >> 11) * 32 + ((mb & 2047) >> 6)) * 16384;
    const int jp4 = (g4 & 1) * 4;
    const int g4h = g4 >> 1;
#pragma unroll
    for (int j = 0; j < 4; ++j) {
      int col = wave * 64 + j * 16 + m;
      float bv = bh[col];
      size_t colb = tb + (size_t)col * 64;
#pragma unroll
      for (int i = 0; i < 4; ++i) {
        int g4a = ((i * 2 + g4h) & 3) ^ sw;
        int h8 = ((i >> 1) & 1) * 8;
        float s0 = silu(acc[i][j][0] + bv);
        float s1 = silu(acc[i][j][1] + bv);
        float s2 = silu(acc[i][j][2] + bv);
        float s3 = silu(acc[i][j][3] + bv);
        *(unsigned*)(vB + colb + g4a * 16 + h8 + jp4) = pk4fp8(s0, s1, s2, s3);
      }
    }
  }
  // ---------- pass 2: gate = silu(normed @ wh[:,256:512] + b) -> bf16 rows ----------
  {
    floatx4 acc[4][4] = {};
#pragma unroll
    for (int ks = 0; ks < 8; ++ks) {
      short8 af[4], bf[4];
#pragma unroll
      for (int i = 0; i < 4; ++i)
        af[i] = *(const short8*)((const char*)Al + (i * 16 + m) * 512 +
                                 (((ks * 4 + g4) ^ (m & 7)) * 16));
#pragma unroll
      for (int j = 0; j < 4; ++j)
        bf[j] = *(const short8*)(wTh + (size_t)(256 + wave * 64 + j * 16 + m) * 256 + ks * 32 + g4 * 8);
#pragma unroll
      for (int i = 0; i < 4; ++i)
#pragma unroll
        for (int j = 0; j < 4; ++j)
          acc[i][j] = __builtin_amdgcn_mfma_f32_16x16x32_bf16(af[i], bf[j], acc[i][j], 0, 0, 0);
    }
#pragma unroll
    for (int j = 0; j < 4; ++j) {
      int colg = wave * 64 + j * 16 + m;
      float bv = bh[256 + colg];
#pragma unroll
      for (int i = 0; i < 4; ++i)
#pragma unroll
        for (int r = 0; r < 4; ++r) {
          int row = mb + i * 16 + g4 * 4 + r;
          gout[(size_t)row * CC + colg] = f2bf(silu(acc[i][j][r] + bv));
        }
    }
  }
  // ---------- pass 3: q,k (swapped operands) -> fp8 images ----------
  {
    floatx4 acc[4][4] = {};
#pragma unroll
    for (int ks = 0; ks < 8; ++ks) {
      short8 af[4], bf[4];
#pragma unroll
      for (int i = 0; i < 4; ++i)
        af[i] = *(const short8*)((const char*)Al + (i * 16 + m) * 512 +
                                 (((ks * 4 + g4) ^ (m & 7)) * 16));
#pragma unroll
      for (int j = 0; j < 4; ++j)
        bf[j] = *(const short8*)(wTkv + (size_t)(wave * 64 + j * 16 + m) * 256 + ks * 32 + g4 * 8);
#pragma unroll
      for (int i = 0; i < 4; ++i)
#pragma unroll
        for (int j = 0; j < 4; ++j)
          acc[i][j] = __builtin_amdgcn_mfma_f32_16x16x32_bf16(bf[j], af[i], acc[i][j], 0, 0, 0);
    }
#pragma unroll
    for (int j = 0; j < 4; ++j) {
      int c4 = wave * 64 + j * 16 + g4 * 4;
      float4 g0 = *(const float4*)(gamma + c4);
      float4 b0 = *(const float4*)(beta + c4);
      float4 g1 = *(const float4*)(gamma + CC + c4);
      float4 b1 = *(const float4*)(beta + CC + c4);
      int ks2 = c4 >> 6;
      int hsub = ((c4 >> 5) & 1) * 8 + (c4 & 7);
      int qsub = ((c4 >> 3) & 3) * 16 + hsub;
      int ksub = ((((c4 >> 3) & 3) ^ sw)) * 16 + hsub;
#pragma unroll
      for (int i = 0; i < 4; ++i) {
        int n = mb + i * 16 + m;
        int bb = n >> 11, jj = n & 2047;
        size_t base = (((size_t)bb * 128 + (jj >> 4)) * 4 + ks2) * 1024 + (size_t)m * 64;
        floatx4 z = acc[i][j];
        *(unsigned*)(qout + base + qsub) = pk4fp8(z[0] * g0.x + b0.x, z[1] * g0.y + b0.y,
                                                  z[2] * g0.z + b0.z, z[3] * g0.w + b0.w);
        *(unsigned*)(kout + base + ksub) = pk4fp8(z[0] * g1.x + b1.x, z[1] * g1.y + b1.y,
                                                  z[2] * g1.z + b1.z, z[3] * g1.w + b1.w);
      }
    }
  }
}

// ---- fused attention v11: wave = (i-block 32) x (c-half 128); acc 64 VGPR.
//      24 b128 LDS reads feed 96 MFMAs per wave-tile (was 32:64).
//      K+V LDS DMA dbuf, 1 barrier/tile, per-ib intra-wave bpermute P. ----
__global__ __launch_bounds__(256, 2) void attn_kernel(
    const unsigned char* __restrict__ qB, const unsigned char* __restrict__ kB,
    const unsigned char* __restrict__ vB, const unsigned short* __restrict__ gg,
    unsigned short* __restrict__ og) {
  __shared__ unsigned char Kl[2][16384];
  __shared__ unsigned char Vl[2][16384];
  const int tid = threadIdx.x;
  const int wave = tid >> 6, lane = tid & 63;
  const int m = lane & 15, g4 = lane >> 4;
  const int ih = wave >> 1, ch = wave & 1;   // i-block (32 rows), c-half (128 cols)
  const int id = blockIdx.x;
  const int b = id & 15, bx = id >> 4;       // batch -> XCD co-location
  const int i0 = bx * 64;
  const unsigned char* kimg = kB + (size_t)b * 524288;
  const unsigned char* vimg = vB + (size_t)b * 524288;

  // Q fragments: 2 i-sub-blocks x 4 ks2 (q image unswizzled)
  uint4 qf[2][4];
#pragma unroll
  for (int ib = 0; ib < 2; ++ib)
#pragma unroll
    for (int ks2 = 0; ks2 < 4; ++ks2)
      qf[ib][ks2] = *(const uint4*)(qB +
          ((size_t)(b * 128 + bx * 4 + ih * 2 + ib) * 4 + ks2) * 1024 + m * 64 + g4 * 16);

  floatx4 acc[8][2] = {};   // [cf][ib] : c-half x 2 i-sub-blocks
  const int alo = (m + ((g4 & 1) << 5)) << 2;
  const int ahi = alo + 64;
  const int gsw = (g4 ^ ((m >> 1) & 3)) * 16;

  auto stage = [&](int buf, int t) {
    const unsigned char* kt = kimg + (size_t)t * 16384;
    const unsigned char* vt = vimg + (size_t)t * 16384;
#pragma unroll
    for (int it = 0; it < 4; ++it) {
      int o = (it * 256 + tid) * 16;
      gll16(kt + o, &Kl[buf][o]);
      gll16(vt + o, &Vl[buf][o]);
    }
  };

  stage(0, 0);
  for (int t = 0; t < NTILES; ++t) {
    const int cur = t & 1;
    __syncthreads();  // drains this tile's DMA; prior reads done
    if (t + 1 < NTILES) stage(cur ^ 1, t + 1);
    // ---- QK in two jf-halves (limits live sacc); each kf feeds 4 MFMAs ----
    unsigned pk[2][4];   // [ib][jf]
#pragma unroll
    for (int jh2 = 0; jh2 < 2; ++jh2) {
      floatx4 sacc[2][2] = {};   // [jf2][ib]
#pragma unroll
      for (int ks2 = 0; ks2 < 4; ++ks2)
#pragma unroll
        for (int jf2 = 0; jf2 < 2; ++jf2) {
          int jf = jh2 * 2 + jf2;
          uint4 kf = *(const uint4*)(&Kl[cur][(jf * 4 + ks2) * 1024 + m * 64 + gsw]);
          long klo = lo64(kf), khi = hi64(kf);
#pragma unroll
          for (int ib = 0; ib < 2; ++ib) {
            sacc[jf2][ib] = __builtin_amdgcn_mfma_f32_16x16x32_fp8_fp8(
                klo, lo64(qf[ib][ks2]), sacc[jf2][ib], 0, 0, 0);
            sacc[jf2][ib] = __builtin_amdgcn_mfma_f32_16x16x32_fp8_fp8(
                khi, hi64(qf[ib][ks2]), sacc[jf2][ib], 0, 0, 0);
          }
        }
#pragma unroll
      for (int jf2 = 0; jf2 < 2; ++jf2)
#pragma unroll
        for (int ib = 0; ib < 2; ++ib) {
          float p0 = fmaxf(sacc[jf2][ib][0], 0.0f) * 0.0625f;
          float p1 = fmaxf(sacc[jf2][ib][1], 0.0f) * 0.0625f;
          float p2 = fmaxf(sacc[jf2][ib][2], 0.0f) * 0.0625f;
          float p3 = fmaxf(sacc[jf2][ib][3], 0.0f) * 0.0625f;
          pk[ib][jh2 * 2 + jf2] = pk4fp8(p0 * p0, p1 * p1, p2 * p2, p3 * p3);
        }
    }
    // ---- per-ib intra-wave exchange: ap[ib][kk] = P'[i=m][j = kk*32 + g4*8 ..] ----
    long ap[2][2];
#pragma unroll
    for (int ib = 0; ib < 2; ++ib)
#pragma unroll
      for (int kk = 0; kk < 2; ++kk) {
        int A0 = __builtin_amdgcn_ds_bpermute(alo, (int)pk[ib][2 * kk]);
        int B0 = __builtin_amdgcn_ds_bpermute(alo, (int)pk[ib][2 * kk + 1]);
        int C0 = __builtin_amdgcn_ds_bpermute(ahi, (int)pk[ib][2 * kk]);
        int D0 = __builtin_amdgcn_ds_bpermute(ahi, (int)pk[ib][2 * kk + 1]);
        unsigned lo = (g4 & 2) ? (unsigned)B0 : (unsigned)A0;
        unsigned hi = (g4 & 2) ? (unsigned)D0 : (unsigned)C0;
        ap[ib][kk] = (long)(((unsigned long long)hi << 32) | lo);
      }
    // ---- PV: c-half only; each vfr feeds 4 MFMAs (2 ib x 2 kk) ----
#pragma unroll
    for (int cf = 0; cf < 8; ++cf) {
      int c = ch * 128 + cf * 16 + m;
      uint4 vfr = *(const uint4*)(&Vl[cur][c * 64 + gsw]);
      long vlo = lo64(vfr), vhi = hi64(vfr);
#pragma unroll
      for (int ib = 0; ib < 2; ++ib) {
        acc[cf][ib] = __builtin_amdgcn_mfma_f32_16x16x32_fp8_fp8(ap[ib][0], vlo, acc[cf][ib], 0, 0, 0);
        acc[cf][ib] = __builtin_amdgcn_mfma_f32_16x16x32_fp8_fp8(ap[ib][1], vhi, acc[cf][ib], 0, 0, 0);
      }
    }
  }
  // ---- epilogue: scale 2^-14, gate, bf16 store ----
  const float sc = 1.0f / 16384.0f;
  const size_t bo = (size_t)b * NN * CC;
#pragma unroll
  for (int cf = 0; cf < 8; ++cf)
#pragma unroll
    for (int ib = 0; ib < 2; ++ib)
#pragma unroll
      for (int r = 0; r < 4; ++r) {
        int row = i0 + ih * 32 + ib * 16 + g4 * 4 + r;
        int col = ch * 128 + cf * 16 + m;
        size_t off = bo + (size_t)row * CC + col;
        og[off] = f2bf(acc[cf][ib][r] * sc * bf2f(gg[off]));
      }
}

// --------- GEMM5: (V*gate) @ w_proj + b_proj + x -> fp32 out ---------
__global__ __launch_bounds__(256) void gemm_proj(
    const unsigned short* __restrict__ A, const unsigned short* __restrict__ BT,
    const float* __restrict__ bias, const float* __restrict__ xres,
    float* __restrict__ out) {
  int wave = threadIdx.x >> 6, lane = threadIdx.x & 63;
  int m = lane & 15, g4 = lane >> 4, kb = g4 * 8;
  int m0 = blockIdx.x * 128 + (wave & 1) * 64;
  int n0 = blockIdx.y * 128 + (wave >> 1) * 64;
  floatx4 acc[4][4] = {};
#pragma unroll
  for (int ks = 0; ks < 8; ++ks) {
    short8 af[4], bf[4];
#pragma unroll
    for (int i = 0; i < 4; ++i)
      af[i] = *(const short8*)(A + (size_t)(m0 + i * 16 + m) * CC + ks * 32 + kb);
#pragma unroll
    for (int j = 0; j < 4; ++j)
      bf[j] = *(const short8*)(BT + (size_t)(n0 + j * 16 + m) * CC + ks * 32 + kb);
#pragma unroll
    for (int i = 0; i < 4; ++i)
#pragma unroll
      for (int j = 0; j < 4; ++j)
        acc[i][j] = __builtin_amdgcn_mfma_f32_16x16x32_bf16(af[i], bf[j], acc[i][j], 0, 0, 0);
  }
#pragma unroll
  for (int j = 0; j < 4; ++j) {
    int col = n0 + j * 16 + m;
    float bv = bias[col];
#pragma unroll
    for (int i = 0; i < 4; ++i)
#pragma unroll
      for (int r = 0; r < 4; ++r) {
        int row = m0 + i * 16 + g4 * 4 + r;
        size_t rr = (size_t)row * CC;
        out[rr + col] = acc[i][j][r] + bv + xres[rr + col];
      }
  }
}

extern "C" void kernel_launch(void* const* d_in, const int* in_sizes, int n_in,
                              void* d_out, int out_size, void* d_ws, size_t ws_size,
                              hipStream_t stream) {
  const float* x        = (const float*)d_in[0];
  const float* ln_w     = (const float*)d_in[3];
  const float* ln_b     = (const float*)d_in[4];
  const float* w_hidden = (const float*)d_in[5];
  const float* b_hidden = (const float*)d_in[6];
  const float* w_kv     = (const float*)d_in[7];
  const float* gamma    = (const float*)d_in[8];
  const float* beta     = (const float*)d_in[9];
  const float* w_proj   = (const float*)d_in[10];
  const float* b_proj   = (const float*)d_in[11];
  float* out = (float*)d_out;
  char* ws = (char*)d_ws;

  const size_t SZ = (size_t)BN * CC * 2;  // one bf16 (BN x C) buffer (bytes)
  const size_t HZ = SZ / 2;               // one fp8 buffer
  unsigned short* slot0 = (unsigned short*)(ws);            // attn out (V*gate)
  unsigned short* gbuf  = (unsigned short*)(ws + SZ);
  unsigned char*  qB    = (unsigned char*)(ws + 2 * SZ);
  unsigned char*  kB    = (unsigned char*)(ws + 2 * SZ + HZ);
  unsigned char*  vB    = (unsigned char*)(ws + 2 * SZ + 2 * HZ);
  unsigned short* wTh   = (unsigned short*)(ws + 2 * SZ + 3 * HZ);
  unsigned short* wTkv  = (unsigned short*)(ws + 2 * SZ + 3 * HZ + 512 * 256 * 2);
  unsigned short* wTp   = (unsigned short*)(ws + 2 * SZ + 3 * HZ + 512 * 256 * 2 + 256 * 256 * 2);

  wconv_kernel<<<64, 256, 0, stream>>>(w_hidden, w_kv, w_proj, wTh, wTkv, wTp);
  producer_kernel<<<BN / 64, 256, 0, stream>>>(
      x, ln_w, ln_b, wTh, b_hidden, wTkv, gamma, beta, vB, gbuf, qB, kB);
  attn_kernel<<<512, 256, 0, stream>>>(qB, kB, vB, gbuf, slot0);
  gemm_proj<<<dim3(BN / 128, 2), 256, 0, stream>>>(slot0, wTp, b_proj, x, out);
}

// Round 18
// 163.274 us; speedup vs baseline: 1.0289x; 1.0289x over previous
//
#include <hip/hip_runtime.h>

#define BN 32768
#define NB 16
#define NN 2048
#define CC 256
#define JT 64
#define NTILES (NN / JT)

using short8  = __attribute__((ext_vector_type(8))) short;
using floatx4 = __attribute__((ext_vector_type(4))) float;

__device__ __forceinline__ unsigned short f2bf(float f) {
  unsigned u = __builtin_bit_cast(unsigned, f);
  u += 0x7fffu + ((u >> 16) & 1u);
  return (unsigned short)(u >> 16);
}
__device__ __forceinline__ float bf2f(unsigned short h) {
  unsigned u = ((unsigned)h) << 16;
  return __builtin_bit_cast(float, u);
}
__device__ __forceinline__ unsigned pk4fp8(float a, float b, float c, float d) {
  unsigned u = __builtin_amdgcn_cvt_pk_fp8_f32(c, d, 0, true);
  return __builtin_amdgcn_cvt_pk_fp8_f32(a, b, (int)u, false);
}
__device__ __forceinline__ long lo64(uint4 v) {
  uint2 t; t.x = v.x; t.y = v.y; return __builtin_bit_cast(long, t);
}
__device__ __forceinline__ long hi64(uint4 v) {
  uint2 t; t.x = v.z; t.y = v.w; return __builtin_bit_cast(long, t);
}
__device__ __forceinline__ void gll16(const void* g, void* l) {
  __builtin_amdgcn_global_load_lds(
      (const __attribute__((address_space(1))) void*)g,
      (__attribute__((address_space(3))) void*)l, 16, 0, 0);
}
__device__ __forceinline__ float silu(float h) {
  return h / (1.0f + __expf(-h));
}

// --- weight transposes via LDS tiles (coalesced both sides), fp32 KxN -> bf16 NxK ---
__global__ __launch_bounds__(256) void wconv_kernel(
    const float* __restrict__ wh, const float* __restrict__ wkv,
    const float* __restrict__ wp,
    unsigned short* __restrict__ wTh, unsigned short* __restrict__ wTkv,
    unsigned short* __restrict__ wTp) {
  __shared__ float T[64][65];
  int bid = blockIdx.x;
  const float* src; unsigned short* dst; int N, kt, nt;
  if (bid < 32)      { src = wh;  dst = wTh;  N = 512; kt = bid >> 3;        nt = bid & 7; }
  else if (bid < 48) { src = wkv; dst = wTkv; N = 256; kt = (bid - 32) >> 2; nt = (bid - 32) & 3; }
  else               { src = wp;  dst = wTp;  N = 256; kt = (bid - 48) >> 2; nt = (bid - 48) & 3; }
  int k0 = kt * 64, n0 = nt * 64;
  int t = threadIdx.x;
  int r = t >> 2, c0 = (t & 3) * 16;
#pragma unroll
  for (int e = 0; e < 4; ++e)
    *(float4*)(&T[r][c0 + e * 4]) =
        *(const float4*)(src + (size_t)(k0 + r) * N + n0 + c0 + e * 4);
  __syncthreads();
#pragma unroll
  for (int e = 0; e < 16; ++e)
    dst[(size_t)(n0 + r) * 256 + k0 + c0 + e] = f2bf(T[c0 + e][r]);
}

// ==== fused producer v4: m-tile 32, MERGED ks-loop (v+gate+qk), grid 1024 ====
__global__ __launch_bounds__(256) void producer_kernel(
    const float* __restrict__ x, const float* __restrict__ lw,
    const float* __restrict__ lb,
    const unsigned short* __restrict__ wTh, const float* __restrict__ bh,
    const unsigned short* __restrict__ wTkv,
    const float* __restrict__ gamma, const float* __restrict__ beta,
    unsigned char* __restrict__ vB, unsigned short* __restrict__ gout,
    unsigned char* __restrict__ qout, unsigned char* __restrict__ kout) {
  __shared__ unsigned short Al[32 * 256];   // 16 KB swizzled bf16 normed tile
  const int t = threadIdx.x;
  const int mb = blockIdx.x * 32;
  // ---- LN: 8 threads/row, two reads (no register retention of x) ----
  {
    int r = t >> 3, q = t & 7;
    const float4* xp = (const float4*)(x + (size_t)(mb + r) * CC + q * 32);
    float s = 0.0f, s2 = 0.0f;
#pragma unroll
    for (int f = 0; f < 8; ++f) {
      float4 v = xp[f];
      s  += v.x + v.y + v.z + v.w;
      s2 += v.x * v.x + v.y * v.y + v.z * v.z + v.w * v.w;
    }
    s  += __shfl_xor(s, 1);  s  += __shfl_xor(s, 2);  s  += __shfl_xor(s, 4);
    s2 += __shfl_xor(s2, 1); s2 += __shfl_xor(s2, 2); s2 += __shfl_xor(s2, 4);
    float mu = s * (1.0f / CC);
    float rs = rsqrtf(s2 * (1.0f / CC) - mu * mu + 1e-5f);
    const float4* lwp = (const float4*)(lw + q * 32);
    const float4* lbp = (const float4*)(lb + q * 32);
    asm volatile("" ::: "memory");   // force re-read instead of retaining xv
#pragma unroll
    for (int f = 0; f < 8; ++f) {
      float4 v = xp[f];
      float4 w = lwp[f], b = lbp[f];
      ushort4 o;
      o.x = f2bf((v.x - mu) * rs * w.x + b.x);
      o.y = f2bf((v.y - mu) * rs * w.y + b.y);
      o.z = f2bf((v.z - mu) * rs * w.z + b.z);
      o.w = f2bf((v.w - mu) * rs * w.w + b.w);
      int c16 = q * 4 + (f >> 1);
      *(ushort4*)((char*)Al + r * 512 + ((c16 ^ (r & 7)) * 16) + (f & 1) * 8) = o;
    }
  }
  __syncthreads();
  const int wave = t >> 6, lane = t & 63;
  const int m = lane & 15, g4 = lane >> 4;
  const int sw = (m >> 1) & 3;
  const int mbo = mb & 32;
  // ---------- merged ks-loop: v + gate + qk accumulate together ----------
  floatx4 accv[2][4] = {}, accg[2][4] = {}, acck[2][4] = {};
#pragma unroll
  for (int ks = 0; ks < 8; ++ks) {
    short8 af[2], bfv[4], bfg[4], bfk[4];
#pragma unroll
    for (int i = 0; i < 2; ++i)
      af[i] = *(const short8*)((const char*)Al + (i * 16 + m) * 512 +
                               (((ks * 4 + g4) ^ (m & 7)) * 16));
#pragma unroll
    for (int j = 0; j < 4; ++j) {
      size_t roff = (size_t)(wave * 64 + j * 16 + m) * 256 + ks * 32 + g4 * 8;
      bfv[j] = *(const short8*)(wTh + roff);
      bfg[j] = *(const short8*)(wTh + 65536 + roff);   // +256 rows
      bfk[j] = *(const short8*)(wTkv + roff);
    }
#pragma unroll
    for (int i = 0; i < 2; ++i)
#pragma unroll
      for (int j = 0; j < 4; ++j) {
        accv[i][j] = __builtin_amdgcn_mfma_f32_16x16x32_bf16(af[i], bfv[j], accv[i][j], 0, 0, 0);
        accg[i][j] = __builtin_amdgcn_mfma_f32_16x16x32_bf16(af[i], bfg[j], accg[i][j], 0, 0, 0);
        acck[i][j] = __builtin_amdgcn_mfma_f32_16x16x32_bf16(bfk[j], af[i], acck[i][j], 0, 0, 0);
      }
  }
  // ---------- epilogue 1: v -> fp8 image ----------
  {
    const size_t tb = ((size_t)(mb >> 11) * 32 + ((mb & 2047) >> 6)) * 16384;
#pragma unroll
    for (int j = 0; j < 4; ++j) {
      int col = wave * 64 + j * 16 + m;
      float bv = bh[col];
      size_t colb = tb + (size_t)col * 64;
#pragma unroll
      for (int i = 0; i < 2; ++i) {
        int jjq = mbo + i * 16 + g4 * 4;
        int g4a = ((jjq >> 3) & 3) ^ sw;
        int h8 = ((jjq >> 5) & 1) * 8;
        int jp4 = jjq & 4;
        float s0 = silu(accv[i][j][0] + bv);
        float s1 = silu(accv[i][j][1] + bv);
        float s2 = silu(accv[i][j][2] + bv);
        float s3 = silu(accv[i][j][3] + bv);
        *(unsigned*)(vB + colb + g4a * 16 + h8 + jp4) = pk4fp8(s0, s1, s2, s3);
      }
    }
  }
  // ---------- epilogue 2: gate -> bf16 rows ----------
  {
#pragma unroll
    for (int j = 0; j < 4; ++j) {
      int colg = wave * 64 + j * 16 + m;
      float bv = bh[256 + colg];
#pragma unroll
      for (int i = 0; i < 2; ++i)
#pragma unroll
        for (int r = 0; r < 4; ++r) {
          int row = mb + i * 16 + g4 * 4 + r;
          gout[(size_t)row * CC + colg] = f2bf(silu(accg[i][j][r] + bv));
        }
    }
  }
  // ---------- epilogue 3: q,k -> fp8 images ----------
  {
#pragma unroll
    for (int j = 0; j < 4; ++j) {
      int c4 = wave * 64 + j * 16 + g4 * 4;
      float4 g0 = *(const float4*)(gamma + c4);
      float4 b0 = *(const float4*)(beta + c4);
      float4 g1 = *(const float4*)(gamma + CC + c4);
      float4 b1 = *(const float4*)(beta + CC + c4);
      int ks2 = c4 >> 6;
      int hsub = ((c4 >> 5) & 1) * 8 + (c4 & 7);
      int qsub = ((c4 >> 3) & 3) * 16 + hsub;
      int ksub = ((((c4 >> 3) & 3) ^ sw)) * 16 + hsub;
#pragma unroll
      for (int i = 0; i < 2; ++i) {
        int n = mb + i * 16 + m;
        int bb = n >> 11, jj = n & 2047;
        size_t base = (((size_t)bb * 128 + (jj >> 4)) * 4 + ks2) * 1024 + (size_t)m * 64;
        floatx4 z = acck[i][j];
        *(unsigned*)(qout + base + qsub) = pk4fp8(z[0] * g0.x + b0.x, z[1] * g0.y + b0.y,
                                                  z[2] * g0.z + b0.z, z[3] * g0.w + b0.w);
        *(unsigned*)(kout + base + ksub) = pk4fp8(z[0] * g1.x + b1.x, z[1] * g1.y + b1.y,
                                                  z[2] * g1.z + b1.z, z[3] * g1.w + b1.w);
      }
    }
  }
}

// ---- fused attention v9 (reverted, best-known): K+V LDS DMA dbuf, 1 barrier/tile,
//      intra-wave bpermute P, XOR-swizzled fragment reads (images pre-swizzled) ----
__global__ __launch_bounds__(256, 2) void attn_kernel(
    const unsigned char* __restrict__ qB, const unsigned char* __restrict__ kB,
    const unsigned char* __restrict__ vB, const unsigned short* __restrict__ gg,
    unsigned short* __restrict__ og) {
  __shared__ unsigned char Kl[2][16384];
  __shared__ unsigned char Vl[2][16384];
  const int tid = threadIdx.x;
  const int wave = tid >> 6, lane = tid & 63;
  const int m = lane & 15, g4 = lane >> 4;
  const int id = blockIdx.x;
  const int b = id & 15, bx = id >> 4;
  const int i0 = bx * 64;
  const unsigned char* kimg = kB + (size_t)b * 524288;
  const unsigned char* vimg = vB + (size_t)b * 524288;

  const int iblk = bx * 4 + wave;
  uint4 qf[4];
#pragma unroll
  for (int ks2 = 0; ks2 < 4; ++ks2)
    qf[ks2] = *(const uint4*)(qB + ((size_t)(b * 128 + iblk) * 4 + ks2) * 1024 + m * 64 + g4 * 16);

  floatx4 acc[16] = {};
  const int alo = (m + ((g4 & 1) << 5)) << 2;
  const int ahi = alo + 64;
  const int gsw = (g4 ^ ((m >> 1) & 3)) * 16;

  auto stage = [&](int buf, int t) {
    const unsigned char* kt = kimg + (size_t)t * 16384;
    const unsigned char* vt = vimg + (size_t)t * 16384;
#pragma unroll
    for (int it = 0; it < 4; ++it) {
      int o = (it * 256 + tid) * 16;
      gll16(kt + o, &Kl[buf][o]);
      gll16(vt + o, &Vl[buf][o]);
    }
  };

  stage(0, 0);
  for (int t = 0; t < NTILES; ++t) {
    const int cur = t & 1;
    __syncthreads();
    if (t + 1 < NTILES) stage(cur ^ 1, t + 1);
    floatx4 sacc[4] = {};
#pragma unroll
    for (int ks2 = 0; ks2 < 4; ++ks2) {
#pragma unroll
      for (int jf = 0; jf < 4; ++jf) {
        uint4 kf = *(const uint4*)(&Kl[cur][(jf * 4 + ks2) * 1024 + m * 64 + gsw]);
        sacc[jf] = __builtin_amdgcn_mfma_f32_16x16x32_fp8_fp8(
            lo64(kf), lo64(qf[ks2]), sacc[jf], 0, 0, 0);
        sacc[jf] = __builtin_amdgcn_mfma_f32_16x16x32_fp8_fp8(
            hi64(kf), hi64(qf[ks2]), sacc[jf], 0, 0, 0);
      }
    }
    unsigned pk[4];
#pragma unroll
    for (int jf = 0; jf < 4; ++jf) {
      float p0 = fmaxf(sacc[jf][0], 0.0f) * 0.0625f;
      float p1 = fmaxf(sacc[jf][1], 0.0f) * 0.0625f;
      float p2 = fmaxf(sacc[jf][2], 0.0f) * 0.0625f;
      float p3 = fmaxf(sacc[jf][3], 0.0f) * 0.0625f;
      pk[jf] = pk4fp8(p0 * p0, p1 * p1, p2 * p2, p3 * p3);
    }
    long ap[2];
#pragma unroll
    for (int kk = 0; kk < 2; ++kk) {
      int A0 = __builtin_amdgcn_ds_bpermute(alo, (int)pk[2 * kk]);
      int B0 = __builtin_amdgcn_ds_bpermute(alo, (int)pk[2 * kk + 1]);
      int C0 = __builtin_amdgcn_ds_bpermute(ahi, (int)pk[2 * kk]);
      int D0 = __builtin_amdgcn_ds_bpermute(ahi, (int)pk[2 * kk + 1]);
      unsigned lo = (g4 & 2) ? (unsigned)B0 : (unsigned)A0;
      unsigned hi = (g4 & 2) ? (unsigned)D0 : (unsigned)C0;
      ap[kk] = (long)(((unsigned long long)hi << 32) | lo);
    }
#pragma unroll
    for (int cf = 0; cf < 16; ++cf) {
      uint4 vfr = *(const uint4*)(&Vl[cur][cf * 1024 + m * 64 + gsw]);
      acc[cf] = __builtin_amdgcn_mfma_f32_16x16x32_fp8_fp8(ap[0], lo64(vfr), acc[cf], 0, 0, 0);
      acc[cf] = __builtin_amdgcn_mfma_f32_16x16x32_fp8_fp8(ap[1], hi64(vfr), acc[cf], 0, 0, 0);
    }
  }
  const float sc = 1.0f / 16384.0f;
  const size_t bo = (size_t)b * NN * CC;
#pragma unroll
  for (int cf = 0; cf < 16; ++cf)
#pragma unroll
    for (int r = 0; r < 4; ++r) {
      int row = i0 + wave * 16 + g4 * 4 + r;
      int col = cf * 16 + m;
      size_t off = bo + (size_t)row * CC + col;
      og[off] = f2bf(acc[cf][r] * sc * bf2f(gg[off]));
    }
}

// --------- GEMM5: (V*gate) @ w_proj + b_proj + x -> fp32 out ---------
__global__ __launch_bounds__(256) void gemm_proj(
    const unsigned short* __restrict__ A, const unsigned short* __restrict__ BT,
    const float* __restrict__ bias, const float* __restrict__ xres,
    float* __restrict__ out) {
  int wave = threadIdx.x >> 6, lane = threadIdx.x & 63;
  int m = lane & 15, g4 = lane >> 4, kb = g4 * 8;
  int m0 = blockIdx.x * 128 + (wave & 1) * 64;
  int n0 = blockIdx.y * 128 + (wave >> 1) * 64;
  floatx4 acc[4][4] = {};
#pragma unroll
  for (int ks = 0; ks < 8; ++ks) {
    short8 af[4], bf[4];
#pragma unroll
    for (int i = 0; i < 4; ++i)
      af[i] = *(const short8*)(A + (size_t)(m0 + i * 16 + m) * CC + ks * 32 + kb);
#pragma unroll
    for (int j = 0; j < 4; ++j)
      bf[j] = *(const short8*)(BT + (size_t)(n0 + j * 16 + m) * CC + ks * 32 + kb);
#pragma unroll
    for (int i = 0; i < 4; ++i)
#pragma unroll
      for (int j = 0; j < 4; ++j)
        acc[i][j] = __builtin_amdgcn_mfma_f32_16x16x32_bf16(af[i], bf[j], acc[i][j], 0, 0, 0);
  }
#pragma unroll
  for (int j = 0; j < 4; ++j) {
    int col = n0 + j * 16 + m;
    float bv = bias[col];
#pragma unroll
    for (int i = 0; i < 4; ++i)
#pragma unroll
      for (int r = 0; r < 4; ++r) {
        int row = m0 + i * 16 + g4 * 4 + r;
        size_t rr = (size_t)row * CC;
        out[rr + col] = acc[i][j][r] + bv + xres[rr + col];
      }
  }
}

extern "C" void kernel_launch(void* const* d_in, const int* in_sizes, int n_in,
                              void* d_out, int out_size, void* d_ws, size_t ws_size,
                              hipStream_t stream) {
  const float* x        = (const float*)d_in[0];
  const float* ln_w     = (const float*)d_in[3];
  const float* ln_b     = (const float*)d_in[4];
  const float* w_hidden = (const float*)d_in[5];
  const float* b_hidden = (const float*)d_in[6];
  const float* w_kv     = (const float*)d_in[7];
  const float* gamma    = (const float*)d_in[8];
  const float* beta     = (const float*)d_in[9];
  const float* w_proj   = (const float*)d_in[10];
  const float* b_proj   = (const float*)d_in[11];
  float* out = (float*)d_out;
  char* ws = (char*)d_ws;

  const size_t SZ = (size_t)BN * CC * 2;  // one bf16 (BN x C) buffer (bytes)
  const size_t HZ = SZ / 2;               // one fp8 buffer
  unsigned short* slot0 = (unsigned short*)(ws);            // attn out (V*gate)
  unsigned short* gbuf  = (unsigned short*)(ws + SZ);
  unsigned char*  qB    = (unsigned char*)(ws + 2 * SZ);
  unsigned char*  kB    = (unsigned char*)(ws + 2 * SZ + HZ);
  unsigned char*  vB    = (unsigned char*)(ws + 2 * SZ + 2 * HZ);
  unsigned short* wTh   = (unsigned short*)(ws + 2 * SZ + 3 * HZ);
  unsigned short* wTkv  = (unsigned short*)(ws + 2 * SZ + 3 * HZ + 512 * 256 * 2);
  unsigned short* wTp   = (unsigned short*)(ws + 2 * SZ + 3 * HZ + 512 * 256 * 2 + 256 * 256 * 2);

  wconv_kernel<<<64, 256, 0, stream>>>(w_hidden, w_kv, w_proj, wTh, wTkv, wTp);
  producer_kernel<<<BN / 32, 256, 0, stream>>>(
      x, ln_w, ln_b, wTh, b_hidden, wTkv, gamma, beta, vB, gbuf, qB, kB);
  attn_kernel<<<512, 256, 0, stream>>>(qB, kB, vB, gbuf, slot0);
  gemm_proj<<<dim3(BN / 128, 2), 256, 0, stream>>>(slot0, wTp, b_proj, x, out);
}

// Round 19
// 145.026 us; speedup vs baseline: 1.1584x; 1.1258x over previous
//
#include <hip/hip_runtime.h>

#define BN 32768
#define NB 16
#define NN 2048
#define CC 256
#define JT 64
#define NTILES (NN / JT)

using short8  = __attribute__((ext_vector_type(8))) short;
using floatx4 = __attribute__((ext_vector_type(4))) float;

__device__ __forceinline__ unsigned short f2bf(float f) {
  unsigned u = __builtin_bit_cast(unsigned, f);
  u += 0x7fffu + ((u >> 16) & 1u);
  return (unsigned short)(u >> 16);
}
__device__ __forceinline__ float bf2f(unsigned short h) {
  unsigned u = ((unsigned)h) << 16;
  return __builtin_bit_cast(float, u);
}
__device__ __forceinline__ unsigned pk4fp8(float a, float b, float c, float d) {
  unsigned u = __builtin_amdgcn_cvt_pk_fp8_f32(c, d, 0, true);
  return __builtin_amdgcn_cvt_pk_fp8_f32(a, b, (int)u, false);
}
__device__ __forceinline__ long lo64(uint4 v) {
  uint2 t; t.x = v.x; t.y = v.y; return __builtin_bit_cast(long, t);
}
__device__ __forceinline__ long hi64(uint4 v) {
  uint2 t; t.x = v.z; t.y = v.w; return __builtin_bit_cast(long, t);
}
__device__ __forceinline__ void gll16(const void* g, void* l) {
  __builtin_amdgcn_global_load_lds(
      (const __attribute__((address_space(1))) void*)g,
      (__attribute__((address_space(3))) void*)l, 16, 0, 0);
}
__device__ __forceinline__ float silu(float h) {
  return h / (1.0f + __expf(-h));
}

// --- weight transposes via LDS tiles (coalesced both sides), fp32 KxN -> bf16 NxK ---
__global__ __launch_bounds__(256) void wconv_kernel(
    const float* __restrict__ wh, const float* __restrict__ wkv,
    const float* __restrict__ wp,
    unsigned short* __restrict__ wTh, unsigned short* __restrict__ wTkv,
    unsigned short* __restrict__ wTp) {
  __shared__ float T[64][65];
  int bid = blockIdx.x;
  const float* src; unsigned short* dst; int N, kt, nt;
  if (bid < 32)      { src = wh;  dst = wTh;  N = 512; kt = bid >> 3;        nt = bid & 7; }
  else if (bid < 48) { src = wkv; dst = wTkv; N = 256; kt = (bid - 32) >> 2; nt = (bid - 32) & 3; }
  else               { src = wp;  dst = wTp;  N = 256; kt = (bid - 48) >> 2; nt = (bid - 48) & 3; }
  int k0 = kt * 64, n0 = nt * 64;
  int t = threadIdx.x;
  int r = t >> 2, c0 = (t & 3) * 16;
#pragma unroll
  for (int e = 0; e < 4; ++e)
    *(float4*)(&T[r][c0 + e * 4]) =
        *(const float4*)(src + (size_t)(k0 + r) * N + n0 + c0 + e * 4);
  __syncthreads();
#pragma unroll
  for (int e = 0; e < 16; ++e)
    dst[(size_t)(n0 + r) * 256 + k0 + c0 + e] = f2bf(T[c0 + e][r]);
}

// ==== fused producer (R15 best config): LN once + v + gate + qk, m-tile 64 ====
__global__ __launch_bounds__(256) void producer_kernel(
    const float* __restrict__ x, const float* __restrict__ lw,
    const float* __restrict__ lb,
    const unsigned short* __restrict__ wTh, const float* __restrict__ bh,
    const unsigned short* __restrict__ wTkv,
    const float* __restrict__ gamma, const float* __restrict__ beta,
    unsigned char* __restrict__ vB, unsigned short* __restrict__ gout,
    unsigned char* __restrict__ qout, unsigned char* __restrict__ kout) {
  __shared__ unsigned short Al[64 * 256];   // 32 KB swizzled bf16 normed tile
  const int t = threadIdx.x;
  const int mb = blockIdx.x * 64;
  // ---- LN: 4 threads/row, two reads (no register retention of x) ----
  {
    int r = t >> 2, q = t & 3;
    const float4* xp = (const float4*)(x + (size_t)(mb + r) * CC + q * 64);
    float s = 0.0f, s2 = 0.0f;
#pragma unroll
    for (int f = 0; f < 16; ++f) {
      float4 v = xp[f];
      s  += v.x + v.y + v.z + v.w;
      s2 += v.x * v.x + v.y * v.y + v.z * v.z + v.w * v.w;
    }
    s  += __shfl_xor(s, 1);  s  += __shfl_xor(s, 2);
    s2 += __shfl_xor(s2, 1); s2 += __shfl_xor(s2, 2);
    float mu = s * (1.0f / CC);
    float rs = rsqrtf(s2 * (1.0f / CC) - mu * mu + 1e-5f);
    const float4* lwp = (const float4*)(lw + q * 64);
    const float4* lbp = (const float4*)(lb + q * 64);
    asm volatile("" ::: "memory");   // force re-read instead of retaining xv
#pragma unroll
    for (int f = 0; f < 16; ++f) {
      float4 v = xp[f];
      float4 w = lwp[f], b = lbp[f];
      ushort4 o;
      o.x = f2bf((v.x - mu) * rs * w.x + b.x);
      o.y = f2bf((v.y - mu) * rs * w.y + b.y);
      o.z = f2bf((v.z - mu) * rs * w.z + b.z);
      o.w = f2bf((v.w - mu) * rs * w.w + b.w);
      int c16 = q * 8 + (f >> 1);
      *(ushort4*)((char*)Al + r * 512 + ((c16 ^ (r & 7)) * 16) + (f & 1) * 8) = o;
    }
  }
  __syncthreads();
  const int wave = t >> 6, lane = t & 63;
  const int m = lane & 15, g4 = lane >> 4;
  const int sw = (m >> 1) & 3;
  // ---------- pass 1: v = silu(normed @ wh[:,0:256] + b) -> fp8 image ----------
  {
    floatx4 acc[4][4] = {};
#pragma unroll
    for (int ks = 0; ks < 8; ++ks) {
      short8 af[4], bf[4];
#pragma unroll
      for (int i = 0; i < 4; ++i)
        af[i] = *(const short8*)((const char*)Al + (i * 16 + m) * 512 +
                                 (((ks * 4 + g4) ^ (m & 7)) * 16));
#pragma unroll
      for (int j = 0; j < 4; ++j)
        bf[j] = *(const short8*)(wTh + (size_t)(wave * 64 + j * 16 + m) * 256 + ks * 32 + g4 * 8);
#pragma unroll
      for (int i = 0; i < 4; ++i)
#pragma unroll
        for (int j = 0; j < 4; ++j)
          acc[i][j] = __builtin_amdgcn_mfma_f32_16x16x32_bf16(af[i], bf[j], acc[i][j], 0, 0, 0);
    }
    const size_t tb = ((size_t)(mb >> 11) * 32 + ((mb & 2047) >> 6)) * 16384;
    const int jp4 = (g4 & 1) * 4;
    const int g4h = g4 >> 1;
#pragma unroll
    for (int j = 0; j < 4; ++j) {
      int col = wave * 64 + j * 16 + m;
      float bv = bh[col];
      size_t colb = tb + (size_t)col * 64;
#pragma unroll
      for (int i = 0; i < 4; ++i) {
        int g4a = ((i * 2 + g4h) & 3) ^ sw;
        int h8 = ((i >> 1) & 1) * 8;
        float s0 = silu(acc[i][j][0] + bv);
        float s1 = silu(acc[i][j][1] + bv);
        float s2 = silu(acc[i][j][2] + bv);
        float s3 = silu(acc[i][j][3] + bv);
        *(unsigned*)(vB + colb + g4a * 16 + h8 + jp4) = pk4fp8(s0, s1, s2, s3);
      }
    }
  }
  // ---------- pass 2: gate = silu(normed @ wh[:,256:512] + b) -> bf16 rows ----------
  {
    floatx4 acc[4][4] = {};
#pragma unroll
    for (int ks = 0; ks < 8; ++ks) {
      short8 af[4], bf[4];
#pragma unroll
      for (int i = 0; i < 4; ++i)
        af[i] = *(const short8*)((const char*)Al + (i * 16 + m) * 512 +
                                 (((ks * 4 + g4) ^ (m & 7)) * 16));
#pragma unroll
      for (int j = 0; j < 4; ++j)
        bf[j] = *(const short8*)(wTh + (size_t)(256 + wave * 64 + j * 16 + m) * 256 + ks * 32 + g4 * 8);
#pragma unroll
      for (int i = 0; i < 4; ++i)
#pragma unroll
        for (int j = 0; j < 4; ++j)
          acc[i][j] = __builtin_amdgcn_mfma_f32_16x16x32_bf16(af[i], bf[j], acc[i][j], 0, 0, 0);
    }
#pragma unroll
    for (int j = 0; j < 4; ++j) {
      int colg = wave * 64 + j * 16 + m;
      float bv = bh[256 + colg];
#pragma unroll
      for (int i = 0; i < 4; ++i)
#pragma unroll
        for (int r = 0; r < 4; ++r) {
          int row = mb + i * 16 + g4 * 4 + r;
          gout[(size_t)row * CC + colg] = f2bf(silu(acc[i][j][r] + bv));
        }
    }
  }
  // ---------- pass 3: q,k (swapped operands) -> fp8 images ----------
  {
    floatx4 acc[4][4] = {};
#pragma unroll
    for (int ks = 0; ks < 8; ++ks) {
      short8 af[4], bf[4];
#pragma unroll
      for (int i = 0; i < 4; ++i)
        af[i] = *(const short8*)((const char*)Al + (i * 16 + m) * 512 +
                                 (((ks * 4 + g4) ^ (m & 7)) * 16));
#pragma unroll
      for (int j = 0; j < 4; ++j)
        bf[j] = *(const short8*)(wTkv + (size_t)(wave * 64 + j * 16 + m) * 256 + ks * 32 + g4 * 8);
#pragma unroll
      for (int i = 0; i < 4; ++i)
#pragma unroll
        for (int j = 0; j < 4; ++j)
          acc[i][j] = __builtin_amdgcn_mfma_f32_16x16x32_bf16(bf[j], af[i], acc[i][j], 0, 0, 0);
    }
#pragma unroll
    for (int j = 0; j < 4; ++j) {
      int c4 = wave * 64 + j * 16 + g4 * 4;
      float4 g0 = *(const float4*)(gamma + c4);
      float4 b0 = *(const float4*)(beta + c4);
      float4 g1 = *(const float4*)(gamma + CC + c4);
      float4 b1 = *(const float4*)(beta + CC + c4);
      int ks2 = c4 >> 6;
      int hsub = ((c4 >> 5) & 1) * 8 + (c4 & 7);
      int qsub = ((c4 >> 3) & 3) * 16 + hsub;
      int ksub = ((((c4 >> 3) & 3) ^ sw)) * 16 + hsub;
#pragma unroll
      for (int i = 0; i < 4; ++i) {
        int n = mb + i * 16 + m;
        int bb = n >> 11, jj = n & 2047;
        size_t base = (((size_t)bb * 128 + (jj >> 4)) * 4 + ks2) * 1024 + (size_t)m * 64;
        floatx4 z = acc[i][j];
        *(unsigned*)(qout + base + qsub) = pk4fp8(z[0] * g0.x + b0.x, z[1] * g0.y + b0.y,
                                                  z[2] * g0.z + b0.z, z[3] * g0.w + b0.w);
        *(unsigned*)(kout + base + ksub) = pk4fp8(z[0] * g1.x + b1.x, z[1] * g1.y + b1.y,
                                                  z[2] * g1.z + b1.z, z[3] * g1.w + b1.w);
      }
    }
  }
}

// ---- fused attention v9 + setprio (T5): K+V LDS DMA dbuf, 1 barrier/tile,
//      intra-wave bpermute P, XOR-swizzled fragment reads ----
__global__ __launch_bounds__(256, 2) void attn_kernel(
    const unsigned char* __restrict__ qB, const unsigned char* __restrict__ kB,
    const unsigned char* __restrict__ vB, const unsigned short* __restrict__ gg,
    unsigned short* __restrict__ og) {
  __shared__ unsigned char Kl[2][16384];
  __shared__ unsigned char Vl[2][16384];
  const int tid = threadIdx.x;
  const int wave = tid >> 6, lane = tid & 63;
  const int m = lane & 15, g4 = lane >> 4;
  const int id = blockIdx.x;
  const int b = id & 15, bx = id >> 4;
  const int i0 = bx * 64;
  const unsigned char* kimg = kB + (size_t)b * 524288;
  const unsigned char* vimg = vB + (size_t)b * 524288;

  const int iblk = bx * 4 + wave;
  uint4 qf[4];
#pragma unroll
  for (int ks2 = 0; ks2 < 4; ++ks2)
    qf[ks2] = *(const uint4*)(qB + ((size_t)(b * 128 + iblk) * 4 + ks2) * 1024 + m * 64 + g4 * 16);

  floatx4 acc[16] = {};
  const int alo = (m + ((g4 & 1) << 5)) << 2;
  const int ahi = alo + 64;
  const int gsw = (g4 ^ ((m >> 1) & 3)) * 16;

  auto stage = [&](int buf, int t) {
    const unsigned char* kt = kimg + (size_t)t * 16384;
    const unsigned char* vt = vimg + (size_t)t * 16384;
#pragma unroll
    for (int it = 0; it < 4; ++it) {
      int o = (it * 256 + tid) * 16;
      gll16(kt + o, &Kl[buf][o]);
      gll16(vt + o, &Vl[buf][o]);
    }
  };

  stage(0, 0);
  for (int t = 0; t < NTILES; ++t) {
    const int cur = t & 1;
    __syncthreads();
    if (t + 1 < NTILES) stage(cur ^ 1, t + 1);
    __builtin_amdgcn_s_setprio(1);   // favor this wave through the MFMA-dense region
    floatx4 sacc[4] = {};
#pragma unroll
    for (int ks2 = 0; ks2 < 4; ++ks2) {
#pragma unroll
      for (int jf = 0; jf < 4; ++jf) {
        uint4 kf = *(const uint4*)(&Kl[cur][(jf * 4 + ks2) * 1024 + m * 64 + gsw]);
        sacc[jf] = __builtin_amdgcn_mfma_f32_16x16x32_fp8_fp8(
            lo64(kf), lo64(qf[ks2]), sacc[jf], 0, 0, 0);
        sacc[jf] = __builtin_amdgcn_mfma_f32_16x16x32_fp8_fp8(
            hi64(kf), hi64(qf[ks2]), sacc[jf], 0, 0, 0);
      }
    }
    unsigned pk[4];
#pragma unroll
    for (int jf = 0; jf < 4; ++jf) {
      float p0 = fmaxf(sacc[jf][0], 0.0f) * 0.0625f;
      float p1 = fmaxf(sacc[jf][1], 0.0f) * 0.0625f;
      float p2 = fmaxf(sacc[jf][2], 0.0f) * 0.0625f;
      float p3 = fmaxf(sacc[jf][3], 0.0f) * 0.0625f;
      pk[jf] = pk4fp8(p0 * p0, p1 * p1, p2 * p2, p3 * p3);
    }
    long ap[2];
#pragma unroll
    for (int kk = 0; kk < 2; ++kk) {
      int A0 = __builtin_amdgcn_ds_bpermute(alo, (int)pk[2 * kk]);
      int B0 = __builtin_amdgcn_ds_bpermute(alo, (int)pk[2 * kk + 1]);
      int C0 = __builtin_amdgcn_ds_bpermute(ahi, (int)pk[2 * kk]);
      int D0 = __builtin_amdgcn_ds_bpermute(ahi, (int)pk[2 * kk + 1]);
      unsigned lo = (g4 & 2) ? (unsigned)B0 : (unsigned)A0;
      unsigned hi = (g4 & 2) ? (unsigned)D0 : (unsigned)C0;
      ap[kk] = (long)(((unsigned long long)hi << 32) | lo);
    }
#pragma unroll
    for (int cf = 0; cf < 16; ++cf) {
      uint4 vfr = *(const uint4*)(&Vl[cur][cf * 1024 + m * 64 + gsw]);
      acc[cf] = __builtin_amdgcn_mfma_f32_16x16x32_fp8_fp8(ap[0], lo64(vfr), acc[cf], 0, 0, 0);
      acc[cf] = __builtin_amdgcn_mfma_f32_16x16x32_fp8_fp8(ap[1], hi64(vfr), acc[cf], 0, 0, 0);
    }
    __builtin_amdgcn_s_setprio(0);
  }
  const float sc = 1.0f / 16384.0f;
  const size_t bo = (size_t)b * NN * CC;
#pragma unroll
  for (int cf = 0; cf < 16; ++cf)
#pragma unroll
    for (int r = 0; r < 4; ++r) {
      int row = i0 + wave * 16 + g4 * 4 + r;
      int col = cf * 16 + m;
      size_t off = bo + (size_t)row * CC + col;
      og[off] = f2bf(acc[cf][r] * sc * bf2f(gg[off]));
    }
}

// --------- GEMM5: (V*gate) @ w_proj + b_proj + x -> fp32 out ---------
__global__ __launch_bounds__(256) void gemm_proj(
    const unsigned short* __restrict__ A, const unsigned short* __restrict__ BT,
    const float* __restrict__ bias, const float* __restrict__ xres,
    float* __restrict__ out) {
  int wave = threadIdx.x >> 6, lane = threadIdx.x & 63;
  int m = lane & 15, g4 = lane >> 4, kb = g4 * 8;
  int m0 = blockIdx.x * 128 + (wave & 1) * 64;
  int n0 = blockIdx.y * 128 + (wave >> 1) * 64;
  floatx4 acc[4][4] = {};
#pragma unroll
  for (int ks = 0; ks < 8; ++ks) {
    short8 af[4], bf[4];
#pragma unroll
    for (int i = 0; i < 4; ++i)
      af[i] = *(const short8*)(A + (size_t)(m0 + i * 16 + m) * CC + ks * 32 + kb);
#pragma unroll
    for (int j = 0; j < 4; ++j)
      bf[j] = *(const short8*)(BT + (size_t)(n0 + j * 16 + m) * CC + ks * 32 + kb);
#pragma unroll
    for (int i = 0; i < 4; ++i)
#pragma unroll
      for (int j = 0; j < 4; ++j)
        acc[i][j] = __builtin_amdgcn_mfma_f32_16x16x32_bf16(af[i], bf[j], acc[i][j], 0, 0, 0);
  }
#pragma unroll
  for (int j = 0; j < 4; ++j) {
    int col = n0 + j * 16 + m;
    float bv = bias[col];
#pragma unroll
    for (int i = 0; i < 4; ++i)
#pragma unroll
      for (int r = 0; r < 4; ++r) {
        int row = m0 + i * 16 + g4 * 4 + r;
        size_t rr = (size_t)row * CC;
        out[rr + col] = acc[i][j][r] + bv + xres[rr + col];
      }
  }
}

extern "C" void kernel_launch(void* const* d_in, const int* in_sizes, int n_in,
                              void* d_out, int out_size, void* d_ws, size_t ws_size,
                              hipStream_t stream) {
  const float* x        = (const float*)d_in[0];
  const float* ln_w     = (const float*)d_in[3];
  const float* ln_b     = (const float*)d_in[4];
  const float* w_hidden = (const float*)d_in[5];
  const float* b_hidden = (const float*)d_in[6];
  const float* w_kv     = (const float*)d_in[7];
  const float* gamma    = (const float*)d_in[8];
  const float* beta     = (const float*)d_in[9];
  const float* w_proj   = (const float*)d_in[10];
  const float* b_proj   = (const float*)d_in[11];
  float* out = (float*)d_out;
  char* ws = (char*)d_ws;

  const size_t SZ = (size_t)BN * CC * 2;  // one bf16 (BN x C) buffer (bytes)
  const size_t HZ = SZ / 2;               // one fp8 buffer
  unsigned short* slot0 = (unsigned short*)(ws);            // attn out (V*gate)
  unsigned short* gbuf  = (unsigned short*)(ws + SZ);
  unsigned char*  qB    = (unsigned char*)(ws + 2 * SZ);
  unsigned char*  kB    = (unsigned char*)(ws + 2 * SZ + HZ);
  unsigned char*  vB    = (unsigned char*)(ws + 2 * SZ + 2 * HZ);
  unsigned short* wTh   = (unsigned short*)(ws + 2 * SZ + 3 * HZ);
  unsigned short* wTkv  = (unsigned short*)(ws + 2 * SZ + 3 * HZ + 512 * 256 * 2);
  unsigned short* wTp   = (unsigned short*)(ws + 2 * SZ + 3 * HZ + 512 * 256 * 2 + 256 * 256 * 2);

  wconv_kernel<<<64, 256, 0, stream>>>(w_hidden, w_kv, w_proj, wTh, wTkv, wTp);
  producer_kernel<<<BN / 64, 256, 0, stream>>>(
      x, ln_w, ln_b, wTh, b_hidden, wTkv, gamma, beta, vB, gbuf, qB, kB);
  attn_kernel<<<512, 256, 0, stream>>>(qB, kB, vB, gbuf, slot0);
  gemm_proj<<<dim3(BN / 128, 2), 256, 0, stream>>>(slot0, wTp, b_proj, x, out);
}

// Round 20
// 142.837 us; speedup vs baseline: 1.1761x; 1.0153x over previous
//
#include <hip/hip_runtime.h>

#define BN 32768
#define NB 16
#define NN 2048
#define CC 256
#define JT 64
#define NTILES (NN / JT)

using short8  = __attribute__((ext_vector_type(8))) short;
using floatx4 = __attribute__((ext_vector_type(4))) float;

__device__ __forceinline__ unsigned short f2bf(float f) {
  unsigned u = __builtin_bit_cast(unsigned, f);
  u += 0x7fffu + ((u >> 16) & 1u);
  return (unsigned short)(u >> 16);
}
__device__ __forceinline__ float bf2f(unsigned short h) {
  unsigned u = ((unsigned)h) << 16;
  return __builtin_bit_cast(float, u);
}
__device__ __forceinline__ unsigned pk4fp8(float a, float b, float c, float d) {
  unsigned u = __builtin_amdgcn_cvt_pk_fp8_f32(c, d, 0, true);
  return __builtin_amdgcn_cvt_pk_fp8_f32(a, b, (int)u, false);
}
__device__ __forceinline__ long lo64(uint4 v) {
  uint2 t; t.x = v.x; t.y = v.y; return __builtin_bit_cast(long, t);
}
__device__ __forceinline__ long hi64(uint4 v) {
  uint2 t; t.x = v.z; t.y = v.w; return __builtin_bit_cast(long, t);
}
__device__ __forceinline__ void gll16(const void* g, void* l) {
  __builtin_amdgcn_global_load_lds(
      (const __attribute__((address_space(1))) void*)g,
      (__attribute__((address_space(3))) void*)l, 16, 0, 0);
}
__device__ __forceinline__ float silu(float h) {
  return h / (1.0f + __expf(-h));
}

// --- weight transposes via LDS tiles (coalesced both sides), fp32 KxN -> bf16 NxK ---
__global__ __launch_bounds__(256) void wconv_kernel(
    const float* __restrict__ wh, const float* __restrict__ wkv,
    const float* __restrict__ wp,
    unsigned short* __restrict__ wTh, unsigned short* __restrict__ wTkv,
    unsigned short* __restrict__ wTp) {
  __shared__ float T[64][65];
  int bid = blockIdx.x;
  const float* src; unsigned short* dst; int N, kt, nt;
  if (bid < 32)      { src = wh;  dst = wTh;  N = 512; kt = bid >> 3;        nt = bid & 7; }
  else if (bid < 48) { src = wkv; dst = wTkv; N = 256; kt = (bid - 32) >> 2; nt = (bid - 32) & 3; }
  else               { src = wp;  dst = wTp;  N = 256; kt = (bid - 48) >> 2; nt = (bid - 48) & 3; }
  int k0 = kt * 64, n0 = nt * 64;
  int t = threadIdx.x;
  int r = t >> 2, c0 = (t & 3) * 16;
#pragma unroll
  for (int e = 0; e < 4; ++e)
    *(float4*)(&T[r][c0 + e * 4]) =
        *(const float4*)(src + (size_t)(k0 + r) * N + n0 + c0 + e * 4);
  __syncthreads();
#pragma unroll
  for (int e = 0; e < 16; ++e)
    dst[(size_t)(n0 + r) * 256 + k0 + c0 + e] = f2bf(T[c0 + e][r]);
}

// ==== fused producer (R15 config + T5 setprio): LN once + v + gate + qk, m-tile 64 ====
__global__ __launch_bounds__(256) void producer_kernel(
    const float* __restrict__ x, const float* __restrict__ lw,
    const float* __restrict__ lb,
    const unsigned short* __restrict__ wTh, const float* __restrict__ bh,
    const unsigned short* __restrict__ wTkv,
    const float* __restrict__ gamma, const float* __restrict__ beta,
    unsigned char* __restrict__ vB, unsigned short* __restrict__ gout,
    unsigned char* __restrict__ qout, unsigned char* __restrict__ kout) {
  __shared__ unsigned short Al[64 * 256];   // 32 KB swizzled bf16 normed tile
  const int t = threadIdx.x;
  const int mb = blockIdx.x * 64;
  // ---- LN: 4 threads/row, two reads (no register retention of x) ----
  {
    int r = t >> 2, q = t & 3;
    const float4* xp = (const float4*)(x + (size_t)(mb + r) * CC + q * 64);
    float s = 0.0f, s2 = 0.0f;
#pragma unroll
    for (int f = 0; f < 16; ++f) {
      float4 v = xp[f];
      s  += v.x + v.y + v.z + v.w;
      s2 += v.x * v.x + v.y * v.y + v.z * v.z + v.w * v.w;
    }
    s  += __shfl_xor(s, 1);  s  += __shfl_xor(s, 2);
    s2 += __shfl_xor(s2, 1); s2 += __shfl_xor(s2, 2);
    float mu = s * (1.0f / CC);
    float rs = rsqrtf(s2 * (1.0f / CC) - mu * mu + 1e-5f);
    const float4* lwp = (const float4*)(lw + q * 64);
    const float4* lbp = (const float4*)(lb + q * 64);
    asm volatile("" ::: "memory");   // force re-read instead of retaining xv
#pragma unroll
    for (int f = 0; f < 16; ++f) {
      float4 v = xp[f];
      float4 w = lwp[f], b = lbp[f];
      ushort4 o;
      o.x = f2bf((v.x - mu) * rs * w.x + b.x);
      o.y = f2bf((v.y - mu) * rs * w.y + b.y);
      o.z = f2bf((v.z - mu) * rs * w.z + b.z);
      o.w = f2bf((v.w - mu) * rs * w.w + b.w);
      int c16 = q * 8 + (f >> 1);
      *(ushort4*)((char*)Al + r * 512 + ((c16 ^ (r & 7)) * 16) + (f & 1) * 8) = o;
    }
  }
  __syncthreads();
  const int wave = t >> 6, lane = t & 63;
  const int m = lane & 15, g4 = lane >> 4;
  const int sw = (m >> 1) & 3;
  // ---------- pass 1: v = silu(normed @ wh[:,0:256] + b) -> fp8 image ----------
  {
    floatx4 acc[4][4] = {};
    __builtin_amdgcn_s_setprio(1);
#pragma unroll
    for (int ks = 0; ks < 8; ++ks) {
      short8 af[4], bf[4];
#pragma unroll
      for (int i = 0; i < 4; ++i)
        af[i] = *(const short8*)((const char*)Al + (i * 16 + m) * 512 +
                                 (((ks * 4 + g4) ^ (m & 7)) * 16));
#pragma unroll
      for (int j = 0; j < 4; ++j)
        bf[j] = *(const short8*)(wTh + (size_t)(wave * 64 + j * 16 + m) * 256 + ks * 32 + g4 * 8);
#pragma unroll
      for (int i = 0; i < 4; ++i)
#pragma unroll
        for (int j = 0; j < 4; ++j)
          acc[i][j] = __builtin_amdgcn_mfma_f32_16x16x32_bf16(af[i], bf[j], acc[i][j], 0, 0, 0);
    }
    __builtin_amdgcn_s_setprio(0);
    const size_t tb = ((size_t)(mb >> 11) * 32 + ((mb & 2047) >> 6)) * 16384;
    const int jp4 = (g4 & 1) * 4;
    const int g4h = g4 >> 1;
#pragma unroll
    for (int j = 0; j < 4; ++j) {
      int col = wave * 64 + j * 16 + m;
      float bv = bh[col];
      size_t colb = tb + (size_t)col * 64;
#pragma unroll
      for (int i = 0; i < 4; ++i) {
        int g4a = ((i * 2 + g4h) & 3) ^ sw;
        int h8 = ((i >> 1) & 1) * 8;
        float s0 = silu(acc[i][j][0] + bv);
        float s1 = silu(acc[i][j][1] + bv);
        float s2 = silu(acc[i][j][2] + bv);
        float s3 = silu(acc[i][j][3] + bv);
        *(unsigned*)(vB + colb + g4a * 16 + h8 + jp4) = pk4fp8(s0, s1, s2, s3);
      }
    }
  }
  // ---------- pass 2: gate = silu(normed @ wh[:,256:512] + b) -> bf16 rows ----------
  {
    floatx4 acc[4][4] = {};
    __builtin_amdgcn_s_setprio(1);
#pragma unroll
    for (int ks = 0; ks < 8; ++ks) {
      short8 af[4], bf[4];
#pragma unroll
      for (int i = 0; i < 4; ++i)
        af[i] = *(const short8*)((const char*)Al + (i * 16 + m) * 512 +
                                 (((ks * 4 + g4) ^ (m & 7)) * 16));
#pragma unroll
      for (int j = 0; j < 4; ++j)
        bf[j] = *(const short8*)(wTh + (size_t)(256 + wave * 64 + j * 16 + m) * 256 + ks * 32 + g4 * 8);
#pragma unroll
      for (int i = 0; i < 4; ++i)
#pragma unroll
        for (int j = 0; j < 4; ++j)
          acc[i][j] = __builtin_amdgcn_mfma_f32_16x16x32_bf16(af[i], bf[j], acc[i][j], 0, 0, 0);
    }
    __builtin_amdgcn_s_setprio(0);
#pragma unroll
    for (int j = 0; j < 4; ++j) {
      int colg = wave * 64 + j * 16 + m;
      float bv = bh[256 + colg];
#pragma unroll
      for (int i = 0; i < 4; ++i)
#pragma unroll
        for (int r = 0; r < 4; ++r) {
          int row = mb + i * 16 + g4 * 4 + r;
          gout[(size_t)row * CC + colg] = f2bf(silu(acc[i][j][r] + bv));
        }
    }
  }
  // ---------- pass 3: q,k (swapped operands) -> fp8 images ----------
  {
    floatx4 acc[4][4] = {};
    __builtin_amdgcn_s_setprio(1);
#pragma unroll
    for (int ks = 0; ks < 8; ++ks) {
      short8 af[4], bf[4];
#pragma unroll
      for (int i = 0; i < 4; ++i)
        af[i] = *(const short8*)((const char*)Al + (i * 16 + m) * 512 +
                                 (((ks * 4 + g4) ^ (m & 7)) * 16));
#pragma unroll
      for (int j = 0; j < 4; ++j)
        bf[j] = *(const short8*)(wTkv + (size_t)(wave * 64 + j * 16 + m) * 256 + ks * 32 + g4 * 8);
#pragma unroll
      for (int i = 0; i < 4; ++i)
#pragma unroll
        for (int j = 0; j < 4; ++j)
          acc[i][j] = __builtin_amdgcn_mfma_f32_16x16x32_bf16(bf[j], af[i], acc[i][j], 0, 0, 0);
    }
    __builtin_amdgcn_s_setprio(0);
#pragma unroll
    for (int j = 0; j < 4; ++j) {
      int c4 = wave * 64 + j * 16 + g4 * 4;
      float4 g0 = *(const float4*)(gamma + c4);
      float4 b0 = *(const float4*)(beta + c4);
      float4 g1 = *(const float4*)(gamma + CC + c4);
      float4 b1 = *(const float4*)(beta + CC + c4);
      int ks2 = c4 >> 6;
      int hsub = ((c4 >> 5) & 1) * 8 + (c4 & 7);
      int qsub = ((c4 >> 3) & 3) * 16 + hsub;
      int ksub = ((((c4 >> 3) & 3) ^ sw)) * 16 + hsub;
#pragma unroll
      for (int i = 0; i < 4; ++i) {
        int n = mb + i * 16 + m;
        int bb = n >> 11, jj = n & 2047;
        size_t base = (((size_t)bb * 128 + (jj >> 4)) * 4 + ks2) * 1024 + (size_t)m * 64;
        floatx4 z = acc[i][j];
        *(unsigned*)(qout + base + qsub) = pk4fp8(z[0] * g0.x + b0.x, z[1] * g0.y + b0.y,
                                                  z[2] * g0.z + b0.z, z[3] * g0.w + b0.w);
        *(unsigned*)(kout + base + ksub) = pk4fp8(z[0] * g1.x + b1.x, z[1] * g1.y + b1.y,
                                                  z[2] * g1.z + b1.z, z[3] * g1.w + b1.w);
      }
    }
  }
}

// ---- fused attention v9 + setprio (T5): K+V LDS DMA dbuf, 1 barrier/tile,
//      intra-wave bpermute P, XOR-swizzled fragment reads ----
__global__ __launch_bounds__(256, 2) void attn_kernel(
    const unsigned char* __restrict__ qB, const unsigned char* __restrict__ kB,
    const unsigned char* __restrict__ vB, const unsigned short* __restrict__ gg,
    unsigned short* __restrict__ og) {
  __shared__ unsigned char Kl[2][16384];
  __shared__ unsigned char Vl[2][16384];
  const int tid = threadIdx.x;
  const int wave = tid >> 6, lane = tid & 63;
  const int m = lane & 15, g4 = lane >> 4;
  const int id = blockIdx.x;
  const int b = id & 15, bx = id >> 4;
  const int i0 = bx * 64;
  const unsigned char* kimg = kB + (size_t)b * 524288;
  const unsigned char* vimg = vB + (size_t)b * 524288;

  const int iblk = bx * 4 + wave;
  uint4 qf[4];
#pragma unroll
  for (int ks2 = 0; ks2 < 4; ++ks2)
    qf[ks2] = *(const uint4*)(qB + ((size_t)(b * 128 + iblk) * 4 + ks2) * 1024 + m * 64 + g4 * 16);

  floatx4 acc[16] = {};
  const int alo = (m + ((g4 & 1) << 5)) << 2;
  const int ahi = alo + 64;
  const int gsw = (g4 ^ ((m >> 1) & 3)) * 16;

  auto stage = [&](int buf, int t) {
    const unsigned char* kt = kimg + (size_t)t * 16384;
    const unsigned char* vt = vimg + (size_t)t * 16384;
#pragma unroll
    for (int it = 0; it < 4; ++it) {
      int o = (it * 256 + tid) * 16;
      gll16(kt + o, &Kl[buf][o]);
      gll16(vt + o, &Vl[buf][o]);
    }
  };

  stage(0, 0);
  for (int t = 0; t < NTILES; ++t) {
    const int cur = t & 1;
    __syncthreads();
    if (t + 1 < NTILES) stage(cur ^ 1, t + 1);
    __builtin_amdgcn_s_setprio(1);   // favor this wave through the MFMA-dense region
    floatx4 sacc[4] = {};
#pragma unroll
    for (int ks2 = 0; ks2 < 4; ++ks2) {
#pragma unroll
      for (int jf = 0; jf < 4; ++jf) {
        uint4 kf = *(const uint4*)(&Kl[cur][(jf * 4 + ks2) * 1024 + m * 64 + gsw]);
        sacc[jf] = __builtin_amdgcn_mfma_f32_16x16x32_fp8_fp8(
            lo64(kf), lo64(qf[ks2]), sacc[jf], 0, 0, 0);
        sacc[jf] = __builtin_amdgcn_mfma_f32_16x16x32_fp8_fp8(
            hi64(kf), hi64(qf[ks2]), sacc[jf], 0, 0, 0);
      }
    }
    unsigned pk[4];
#pragma unroll
    for (int jf = 0; jf < 4; ++jf) {
      float p0 = fmaxf(sacc[jf][0], 0.0f) * 0.0625f;
      float p1 = fmaxf(sacc[jf][1], 0.0f) * 0.0625f;
      float p2 = fmaxf(sacc[jf][2], 0.0f) * 0.0625f;
      float p3 = fmaxf(sacc[jf][3], 0.0f) * 0.0625f;
      pk[jf] = pk4fp8(p0 * p0, p1 * p1, p2 * p2, p3 * p3);
    }
    long ap[2];
#pragma unroll
    for (int kk = 0; kk < 2; ++kk) {
      int A0 = __builtin_amdgcn_ds_bpermute(alo, (int)pk[2 * kk]);
      int B0 = __builtin_amdgcn_ds_bpermute(alo, (int)pk[2 * kk + 1]);
      int C0 = __builtin_amdgcn_ds_bpermute(ahi, (int)pk[2 * kk]);
      int D0 = __builtin_amdgcn_ds_bpermute(ahi, (int)pk[2 * kk + 1]);
      unsigned lo = (g4 & 2) ? (unsigned)B0 : (unsigned)A0;
      unsigned hi = (g4 & 2) ? (unsigned)D0 : (unsigned)C0;
      ap[kk] = (long)(((unsigned long long)hi << 32) | lo);
    }
#pragma unroll
    for (int cf = 0; cf < 16; ++cf) {
      uint4 vfr = *(const uint4*)(&Vl[cur][cf * 1024 + m * 64 + gsw]);
      acc[cf] = __builtin_amdgcn_mfma_f32_16x16x32_fp8_fp8(ap[0], lo64(vfr), acc[cf], 0, 0, 0);
      acc[cf] = __builtin_amdgcn_mfma_f32_16x16x32_fp8_fp8(ap[1], hi64(vfr), acc[cf], 0, 0, 0);
    }
    __builtin_amdgcn_s_setprio(0);
  }
  const float sc = 1.0f / 16384.0f;
  const size_t bo = (size_t)b * NN * CC;
#pragma unroll
  for (int cf = 0; cf < 16; ++cf)
#pragma unroll
    for (int r = 0; r < 4; ++r) {
      int row = i0 + wave * 16 + g4 * 4 + r;
      int col = cf * 16 + m;
      size_t off = bo + (size_t)row * CC + col;
      og[off] = f2bf(acc[cf][r] * sc * bf2f(gg[off]));
    }
}

// --------- GEMM5: (V*gate) @ w_proj + b_proj + x -> fp32 out ---------
__global__ __launch_bounds__(256) void gemm_proj(
    const unsigned short* __restrict__ A, const unsigned short* __restrict__ BT,
    const float* __restrict__ bias, const float* __restrict__ xres,
    float* __restrict__ out) {
  int wave = threadIdx.x >> 6, lane = threadIdx.x & 63;
  int m = lane & 15, g4 = lane >> 4, kb = g4 * 8;
  int m0 = blockIdx.x * 128 + (wave & 1) * 64;
  int n0 = blockIdx.y * 128 + (wave >> 1) * 64;
  floatx4 acc[4][4] = {};
#pragma unroll
  for (int ks = 0; ks < 8; ++ks) {
    short8 af[4], bf[4];
#pragma unroll
    for (int i = 0; i < 4; ++i)
      af[i] = *(const short8*)(A + (size_t)(m0 + i * 16 + m) * CC + ks * 32 + kb);
#pragma unroll
    for (int j = 0; j < 4; ++j)
      bf[j] = *(const short8*)(BT + (size_t)(n0 + j * 16 + m) * CC + ks * 32 + kb);
#pragma unroll
    for (int i = 0; i < 4; ++i)
#pragma unroll
      for (int j = 0; j < 4; ++j)
        acc[i][j] = __builtin_amdgcn_mfma_f32_16x16x32_bf16(af[i], bf[j], acc[i][j], 0, 0, 0);
  }
#pragma unroll
  for (int j = 0; j < 4; ++j) {
    int col = n0 + j * 16 + m;
    float bv = bias[col];
#pragma unroll
    for (int i = 0; i < 4; ++i)
#pragma unroll
      for (int r = 0; r < 4; ++r) {
        int row = m0 + i * 16 + g4 * 4 + r;
        size_t rr = (size_t)row * CC;
        out[rr + col] = acc[i][j][r] + bv + xres[rr + col];
      }
  }
}

extern "C" void kernel_launch(void* const* d_in, const int* in_sizes, int n_in,
                              void* d_out, int out_size, void* d_ws, size_t ws_size,
                              hipStream_t stream) {
  const float* x        = (const float*)d_in[0];
  const float* ln_w     = (const float*)d_in[3];
  const float* ln_b     = (const float*)d_in[4];
  const float* w_hidden = (const float*)d_in[5];
  const float* b_hidden = (const float*)d_in[6];
  const float* w_kv     = (const float*)d_in[7];
  const float* gamma    = (const float*)d_in[8];
  const float* beta     = (const float*)d_in[9];
  const float* w_proj   = (const float*)d_in[10];
  const float* b_proj   = (const float*)d_in[11];
  float* out = (float*)d_out;
  char* ws = (char*)d_ws;

  const size_t SZ = (size_t)BN * CC * 2;  // one bf16 (BN x C) buffer (bytes)
  const size_t HZ = SZ / 2;               // one fp8 buffer
  unsigned short* slot0 = (unsigned short*)(ws);            // attn out (V*gate)
  unsigned short* gbuf  = (unsigned short*)(ws + SZ);
  unsigned char*  qB    = (unsigned char*)(ws + 2 * SZ);
  unsigned char*  kB    = (unsigned char*)(ws + 2 * SZ + HZ);
  unsigned char*  vB    = (unsigned char*)(ws + 2 * SZ + 2 * HZ);
  unsigned short* wTh   = (unsigned short*)(ws + 2 * SZ + 3 * HZ);
  unsigned short* wTkv  = (unsigned short*)(ws + 2 * SZ + 3 * HZ + 512 * 256 * 2);
  unsigned short* wTp   = (unsigned short*)(ws + 2 * SZ + 3 * HZ + 512 * 256 * 2 + 256 * 256 * 2);

  wconv_kernel<<<64, 256, 0, stream>>>(w_hidden, w_kv, w_proj, wTh, wTkv, wTp);
  producer_kernel<<<BN / 64, 256, 0, stream>>>(
      x, ln_w, ln_b, wTh, b_hidden, wTkv, gamma, beta, vB, gbuf, qB, kB);
  attn_kernel<<<512, 256, 0, stream>>>(qB, kB, vB, gbuf, slot0);
  gemm_proj<<<dim3(BN / 128, 2), 256, 0, stream>>>(slot0, wTp, b_proj, x, out);
}